// Round 12
// baseline (149.408 us; speedup 1.0000x reference)
//
#include <hip/hip_runtime.h>
#include <math.h>

#define EPSF 1e-12f
#define ATT_NORM_F 4.0f
#define H_DIM 8
#define C_DIM 16
#define N_NODES 100000
#define SEG_WORDS (N_NODES * H_DIM)   // 800000 words = 3.2 MB
#define NXCD 8

#define CHUNK 192                     // rows per phase per block (= 3*64)
#define PASSES 4                      // row-passes per phase (48 rows each)

typedef float v4f __attribute__((ext_vector_type(4)));
typedef unsigned v4u __attribute__((ext_vector_type(4)));

// ---------------------------------------------------------------------------
// Zero n words.
// ---------------------------------------------------------------------------
__global__ __launch_bounds__(256) void lip_zero(unsigned* __restrict__ p, int n)
{
    int i = blockIdx.x * 256 + threadIdx.x;
    if (i < n) p[i] = 0u;
}

// ---------------------------------------------------------------------------
// LDS-only barrier (R11): orders LDS produce/consume without draining VMEM.
// ---------------------------------------------------------------------------
__device__ __forceinline__ void lds_barrier()
{
    asm volatile("s_waitcnt lgkmcnt(0)\n\ts_barrier" ::: "memory");
}

// ---------------------------------------------------------------------------
// Pass 1, producer/consumer (R11) + per-XCD privatized scatter (R7 redo).
// Waves 0-2 stream x, compute row norms into double-buffered LDS; wave 3
// fires atomicMax into THIS XCD's private table with WORKGROUP scope ->
// the RMW executes at the local L2 (table-resident) instead of the fabric,
// cutting atomic latency ~5-10x. Under R11's structure the scatter wave is
// queue-depth x latency limited (63 / ~1.5us ~= its required rate), so
// latency is now the binding constraint -- unlike R7, where the vmcnt(0)
// barrier drain masked any scope effect.
// Correctness: all writers of part[X] share XCD X's L2 (waves don't
// migrate); dispatch-end writeback publishes partials for the merge.
// ---------------------------------------------------------------------------
__global__ __launch_bounds__(256) void lip_pass1_pc(
    const float* __restrict__ x, const int* __restrict__ index,
    float* __restrict__ norm_x, unsigned* __restrict__ part, int rows)
{
    __shared__ float buf[2][CHUNK];

    const int t = threadIdx.x;
    const int w = t >> 6;                     // wave id 0..3
    const int nchunks = (rows + CHUNK - 1) / CHUNK;
    const v4f* x4 = (const v4f*)x;

    const int rloc = t >> 2;                  // 0..47 (valid for w<3)
    const int lane = t & 3;

    unsigned xcd;
    asm("s_getreg_b32 %0, hwreg(HW_REG_XCC_ID)" : "=s"(xcd));
    unsigned* __restrict__ table = part + (size_t)(xcd & 7) * SEG_WORDS;

    for (int p = 0; ; ++p) {
        int c  = blockIdx.x + p * gridDim.x;          // chunk to stream
        int cp = c - gridDim.x;                       // chunk to scatter
        bool do_s = (c < nchunks);
        bool do_a = (p > 0) && (cp < nchunks);
        if (!do_s && !do_a) break;                    // block-uniform exit

        if (w < 3) {
            if (do_s) {
                int base = c * CHUNK;
                float* b = buf[p & 1];
                #pragma unroll
                for (int j = 0; j < PASSES; ++j) {
                    int r = base + j * 48 + rloc;
                    if (r < rows) {
                        v4f v = __builtin_nontemporal_load(&x4[(size_t)r * 4 + lane]);
                        float s = v.x * v.x + v.y * v.y + v.z * v.z + v.w * v.w;
                        s += __shfl_xor(s, 1);
                        s += __shfl_xor(s, 2);
                        if (lane == 0) {
                            norm_x[r] = s;    // cache-allocating -> LLC for pass2
                            b[j * 48 + rloc] = s;
                        }
                    }
                }
            }
        } else {
            if (do_a) {
                int base = cp * CHUNK;
                const float* b = buf[(p & 1) ^ 1];
                int ln = t & 63;
                #pragma unroll
                for (int k = 0; k < 3; ++k) {
                    int i = k * 64 + ln;              // 0..191
                    int r = base + i;
                    if (r < rows) {
                        float s = b[i];
                        int e = r >> 3;
                        int h = r & 7;
                        // s >= 0: float bits monotone under unsigned max
                        __hip_atomic_fetch_max(&table[index[e] * H_DIM + h],
                                               __float_as_uint(s),
                                               __ATOMIC_RELAXED,
                                               __HIP_MEMORY_SCOPE_WORKGROUP);
                    }
                }
            }
        }
        lds_barrier();   // publishes buf[p&1]; confirms buf[(p-1)&1] drained
    }
}

// ---------------------------------------------------------------------------
// Merge: seg[i] = max over the 8 per-XCD partials (25.6 MB read, L2/LLC-warm).
// ---------------------------------------------------------------------------
__global__ __launch_bounds__(256) void lip_merge(
    const unsigned* __restrict__ part, unsigned* __restrict__ seg, int quads)
{
    int q = blockIdx.x * 256 + threadIdx.x;
    if (q >= quads) return;
    const v4u* p4 = (const v4u*)part;
    const int tq = SEG_WORDS / 4;
    v4u m = p4[q];
    #pragma unroll
    for (int xx = 1; xx < NXCD; ++xx) {
        v4u w = p4[(size_t)xx * tq + q];
        m.x = m.x > w.x ? m.x : w.x;
        m.y = m.y > w.y ? m.y : w.y;
        m.z = m.z > w.z ? m.z : w.z;
        m.w = m.w > w.w ? m.w : w.w;
    }
    ((v4u*)seg)[q] = m;
}

// ---------------------------------------------------------------------------
// Pass 2 (one-shot): out = alpha / (natt * sqrt(seg[idx] + norm_x) + eps)
// ---------------------------------------------------------------------------
__global__ __launch_bounds__(256) void lip_pass2(
    const float* __restrict__ norm_x, const float* __restrict__ alpha,
    const int* __restrict__ index, const unsigned int* __restrict__ seg,
    const float* __restrict__ att_l, const float* __restrict__ att_r,
    float* __restrict__ out, int total)   // total = E*2
{
    __shared__ float s_natt[H_DIM];
    int t = threadIdx.x;
    if (t < H_DIM) {
        float s = 0.f;
        #pragma unroll
        for (int c = 0; c < C_DIM; ++c) {
            float l = att_l[t * C_DIM + c];
            float r = att_r[t * C_DIM + c];
            s += l * l + r * r;
        }
        s_natt[t] = ATT_NORM_F * sqrtf(s);
    }
    __syncthreads();

    int tid = blockIdx.x * 256 + t;
    if (tid >= total) return;

    int e    = tid >> 1;
    int half = tid & 1;
    int idx  = index[e];

    const v4f* nx4 = (const v4f*)norm_x;
    const v4f* al4 = (const v4f*)alpha;
    const v4f* sg4 = (const v4f*)seg;       // bits are non-negative floats

    v4f nx = nx4[tid];                               // LLC-hot
    v4f al = __builtin_nontemporal_load(&al4[tid]);  // cold stream
    v4f sg = sg4[(size_t)idx * 2 + half];            // L2-resident gather

    int h0 = half * 4;
    v4f o;
    o.x = al.x / (s_natt[h0 + 0] * sqrtf(sg.x + nx.x) + EPSF);
    o.y = al.y / (s_natt[h0 + 1] * sqrtf(sg.y + nx.y) + EPSF);
    o.z = al.z / (s_natt[h0 + 2] * sqrtf(sg.z + nx.z) + EPSF);
    o.w = al.w / (s_natt[h0 + 3] * sqrtf(sg.w + nx.w) + EPSF);
    __builtin_nontemporal_store(o, &((v4f*)out)[tid]);
}

// ---------------------------------------------------------------------------
// Fallbacks (ws too small): merged pass1 + recompute pass2 (R4-style).
// ---------------------------------------------------------------------------
__global__ __launch_bounds__(256) void lip_pass1_merged(
    const float* __restrict__ x, const int* __restrict__ index,
    unsigned int* __restrict__ seg, int total /*rows*4*/)
{
    const int stride = gridDim.x * 256;
    const int s0 = blockIdx.x * 256 + threadIdx.x;
    const int lane = s0 & 3;
    const v4f* x4 = (const v4f*)x;
    #pragma unroll 4
    for (int s = s0; s < total; s += stride) {
        v4f v = __builtin_nontemporal_load(&x4[s]);
        float sum = v.x * v.x + v.y * v.y + v.z * v.z + v.w * v.w;
        sum += __shfl_xor(sum, 1);
        sum += __shfl_xor(sum, 2);
        if (lane == 0) {
            int r = s >> 2;
            int e = r >> 3, h = r & 7;
            atomicMax(&seg[(size_t)index[e] * H_DIM + h], __float_as_uint(sum));
        }
    }
}

__global__ __launch_bounds__(256) void lip_pass2_recompute(
    const float* __restrict__ x, const float* __restrict__ alpha,
    const int* __restrict__ index, const unsigned int* __restrict__ seg,
    const float* __restrict__ att_l, const float* __restrict__ att_r,
    float* __restrict__ out, int rows)
{
    __shared__ float s_natt[H_DIM];
    int t = threadIdx.x;
    if (t < H_DIM) {
        float s = 0.f;
        #pragma unroll
        for (int c = 0; c < C_DIM; ++c) {
            float l = att_l[t * C_DIM + c];
            float r = att_r[t * C_DIM + c];
            s += l * l + r * r;
        }
        s_natt[t] = ATT_NORM_F * sqrtf(s);
    }
    __syncthreads();

    int r = blockIdx.x * blockDim.x + t;
    if (r >= rows) return;

    const float4* x4 = (const float4*)x;
    float s = 0.f;
    #pragma unroll
    for (int q = 0; q < 4; ++q) {
        float4 v = x4[(size_t)r * 4 + q];
        s += v.x * v.x + v.y * v.y + v.z * v.z + v.w * v.w;
    }
    int e = r >> 3;
    int h = r & 7;
    float sg = __uint_as_float(seg[(size_t)index[e] * H_DIM + h]);
    out[r] = alpha[r] / (s_natt[h] * sqrtf(sg + s) + EPSF);
}

extern "C" void kernel_launch(void* const* d_in, const int* in_sizes, int n_in,
                              void* d_out, int out_size, void* d_ws, size_t ws_size,
                              hipStream_t stream) {
    const float* x     = (const float*)d_in[0];
    const float* att_l = (const float*)d_in[1];
    const float* att_r = (const float*)d_in[2];
    const float* alpha = (const float*)d_in[3];
    const int*   index = (const int*)d_in[4];

    const int E    = in_sizes[4];
    const int rows = E * H_DIM;

    // ws layout: part[8][SEG_WORDS] | seg[SEG_WORDS] | norm_x[rows]
    size_t part_bytes = (size_t)NXCD * SEG_WORDS * 4;
    size_t seg_off    = (part_bytes + 255) / 256 * 256;
    size_t nx_off     = (seg_off + (size_t)SEG_WORDS * 4 + 255) / 256 * 256;
    size_t need       = nx_off + (size_t)rows * 4;

    if (ws_size >= need) {
        unsigned* part   = (unsigned*)d_ws;
        unsigned* seg    = (unsigned*)((char*)d_ws + seg_off);
        float*    norm_x = (float*)((char*)d_ws + nx_off);

        int zwords = NXCD * SEG_WORDS;
        lip_zero<<<(zwords + 255) / 256, 256, 0, stream>>>(part, zwords);
        lip_pass1_pc<<<2048, 256, 0, stream>>>(x, index, norm_x, part, rows);
        int quads = SEG_WORDS / 4;
        lip_merge<<<(quads + 255) / 256, 256, 0, stream>>>(part, seg, quads);
        lip_pass2<<<((E * 2) + 255) / 256, 256, 0, stream>>>(
            norm_x, alpha, index, seg, att_l, att_r, (float*)d_out, E * 2);
    } else {
        unsigned* seg = (unsigned*)d_ws;
        lip_zero<<<(SEG_WORDS + 255) / 256, 256, 0, stream>>>(seg, SEG_WORDS);
        lip_pass1_merged<<<2048, 256, 0, stream>>>(x, index, seg, rows * 4);
        lip_pass2_recompute<<<(rows + 255) / 256, 256, 0, stream>>>(
            x, alpha, index, seg, att_l, att_r, (float*)d_out, rows);
    }
}

// Round 13
// 142.356 us; speedup vs baseline: 1.0495x; 1.0495x over previous
//
#include <hip/hip_runtime.h>
#include <math.h>

#define EPSF 1e-12f
#define ATT_NORM_F 4.0f
#define H_DIM 8
#define C_DIM 16
#define N_NODES 100000
#define SEG_WORDS (N_NODES * H_DIM)   // 800000 words = 3.2 MB

#define CHUNK 128                     // rows per phase per block
#define PASSES 4                      // row-passes per phase (32 rows each)

typedef float v4f __attribute__((ext_vector_type(4)));

// ---------------------------------------------------------------------------
// Zero the seg table.
// ---------------------------------------------------------------------------
__global__ __launch_bounds__(256) void lip_zero(unsigned* __restrict__ p, int n)
{
    int i = blockIdx.x * 256 + threadIdx.x;
    if (i < n) p[i] = 0u;
}

// ---------------------------------------------------------------------------
// LDS-only barrier (R11): orders LDS produce/consume without draining VMEM.
// __syncthreads would force vmcnt(0) each phase, draining the scatter wave's
// in-flight atomics and the streamers' nt-loads; lgkmcnt(0) covers the only
// real dependency (LDS).
// ---------------------------------------------------------------------------
__device__ __forceinline__ void lds_barrier()
{
    asm volatile("s_waitcnt lgkmcnt(0)\n\ts_barrier" ::: "memory");
}

// ---------------------------------------------------------------------------
// Pass 1, producer/consumer, 2:2 wave split.
// R11 (3 streamers : 1 scatter) left the scatter wave at its throughput cap:
// 192 atomics/phase from one wave ~= queue-depth(63)/fabric-latency(1.5us)
// ~= its max rate, so it arrived last at every phase barrier. With 2 scatter
// waves each firing 64/phase there is 3x headroom; 2 streamer waves still
// satisfy HBM Little's law (independent j-loop loads pipeline in-wave).
// Single seg table + device-scope atomicMax (scope proven irrelevant on
// gfx950: R6/R7/R12).
// ---------------------------------------------------------------------------
__global__ __launch_bounds__(256) void lip_pass1_pc(
    const float* __restrict__ x, const int* __restrict__ index,
    float* __restrict__ norm_x, unsigned* __restrict__ seg, int rows)
{
    __shared__ float buf[2][CHUNK];

    const int t = threadIdx.x;
    const int w = t >> 6;                     // wave id 0..3
    const int nchunks = (rows + CHUNK - 1) / CHUNK;
    const v4f* x4 = (const v4f*)x;

    const int rloc = t >> 2;                  // 0..31 (valid for w<2)
    const int lane = t & 3;

    for (int p = 0; ; ++p) {
        int c  = blockIdx.x + p * gridDim.x;          // chunk to stream
        int cp = c - gridDim.x;                       // chunk to scatter
        bool do_s = (c < nchunks);
        bool do_a = (p > 0) && (cp < nchunks);
        if (!do_s && !do_a) break;                    // block-uniform exit

        if (w < 2) {
            if (do_s) {
                int base = c * CHUNK;
                float* b = buf[p & 1];
                #pragma unroll
                for (int j = 0; j < PASSES; ++j) {
                    int r = base + j * 32 + rloc;
                    if (r < rows) {
                        v4f v = __builtin_nontemporal_load(&x4[(size_t)r * 4 + lane]);
                        float s = v.x * v.x + v.y * v.y + v.z * v.z + v.w * v.w;
                        s += __shfl_xor(s, 1);
                        s += __shfl_xor(s, 2);
                        if (lane == 0) {
                            norm_x[r] = s;    // cache-allocating -> LLC for pass2
                            b[j * 32 + rloc] = s;
                        }
                    }
                }
            }
        } else {
            if (do_a) {
                int base = cp * CHUNK;
                const float* b = buf[(p & 1) ^ 1];
                int i = t - 128;                      // 0..127
                int r = base + i;
                if (r < rows) {
                    float s = b[i];
                    int e = r >> 3;
                    int h = r & 7;
                    // s >= 0: float bits monotone under unsigned max
                    atomicMax(&seg[(size_t)index[e] * H_DIM + h],
                              __float_as_uint(s));
                }
            }
        }
        lds_barrier();   // publishes buf[p&1]; confirms buf[(p-1)&1] drained
    }
}

// ---------------------------------------------------------------------------
// Pass 2 (one-shot): out = alpha / (natt * sqrt(seg[idx] + norm_x) + eps)
// One thread per 4 consecutive heads (float4). seg gather L2-resident;
// norm_x LLC-hot; alpha/out nt streams.
// ---------------------------------------------------------------------------
__global__ __launch_bounds__(256) void lip_pass2(
    const float* __restrict__ norm_x, const float* __restrict__ alpha,
    const int* __restrict__ index, const unsigned int* __restrict__ seg,
    const float* __restrict__ att_l, const float* __restrict__ att_r,
    float* __restrict__ out, int total)   // total = E*2
{
    __shared__ float s_natt[H_DIM];
    int t = threadIdx.x;
    if (t < H_DIM) {
        float s = 0.f;
        #pragma unroll
        for (int c = 0; c < C_DIM; ++c) {
            float l = att_l[t * C_DIM + c];
            float r = att_r[t * C_DIM + c];
            s += l * l + r * r;
        }
        s_natt[t] = ATT_NORM_F * sqrtf(s);
    }
    __syncthreads();

    int tid = blockIdx.x * 256 + t;
    if (tid >= total) return;

    int e    = tid >> 1;
    int half = tid & 1;
    int idx  = index[e];

    const v4f* nx4 = (const v4f*)norm_x;
    const v4f* al4 = (const v4f*)alpha;
    const v4f* sg4 = (const v4f*)seg;       // bits are non-negative floats

    v4f nx = nx4[tid];                               // LLC-hot
    v4f al = __builtin_nontemporal_load(&al4[tid]);  // cold stream
    v4f sg = sg4[(size_t)idx * 2 + half];            // L2-resident gather

    int h0 = half * 4;
    v4f o;
    o.x = al.x / (s_natt[h0 + 0] * sqrtf(sg.x + nx.x) + EPSF);
    o.y = al.y / (s_natt[h0 + 1] * sqrtf(sg.y + nx.y) + EPSF);
    o.z = al.z / (s_natt[h0 + 2] * sqrtf(sg.z + nx.z) + EPSF);
    o.w = al.w / (s_natt[h0 + 3] * sqrtf(sg.w + nx.w) + EPSF);
    __builtin_nontemporal_store(o, &((v4f*)out)[tid]);
}

// ---------------------------------------------------------------------------
// Fallbacks (ws too small): merged pass1 + recompute pass2 (R4-style).
// ---------------------------------------------------------------------------
__global__ __launch_bounds__(256) void lip_pass1_merged(
    const float* __restrict__ x, const int* __restrict__ index,
    unsigned int* __restrict__ seg, int total /*rows*4*/)
{
    const int stride = gridDim.x * 256;
    const int s0 = blockIdx.x * 256 + threadIdx.x;
    const int lane = s0 & 3;
    const v4f* x4 = (const v4f*)x;
    #pragma unroll 4
    for (int s = s0; s < total; s += stride) {
        v4f v = __builtin_nontemporal_load(&x4[s]);
        float sum = v.x * v.x + v.y * v.y + v.z * v.z + v.w * v.w;
        sum += __shfl_xor(sum, 1);
        sum += __shfl_xor(sum, 2);
        if (lane == 0) {
            int r = s >> 2;
            int e = r >> 3, h = r & 7;
            atomicMax(&seg[(size_t)index[e] * H_DIM + h], __float_as_uint(sum));
        }
    }
}

__global__ __launch_bounds__(256) void lip_pass2_recompute(
    const float* __restrict__ x, const float* __restrict__ alpha,
    const int* __restrict__ index, const unsigned int* __restrict__ seg,
    const float* __restrict__ att_l, const float* __restrict__ att_r,
    float* __restrict__ out, int rows)
{
    __shared__ float s_natt[H_DIM];
    int t = threadIdx.x;
    if (t < H_DIM) {
        float s = 0.f;
        #pragma unroll
        for (int c = 0; c < C_DIM; ++c) {
            float l = att_l[t * C_DIM + c];
            float r = att_r[t * C_DIM + c];
            s += l * l + r * r;
        }
        s_natt[t] = ATT_NORM_F * sqrtf(s);
    }
    __syncthreads();

    int r = blockIdx.x * blockDim.x + t;
    if (r >= rows) return;

    const float4* x4 = (const float4*)x;
    float s = 0.f;
    #pragma unroll
    for (int q = 0; q < 4; ++q) {
        float4 v = x4[(size_t)r * 4 + q];
        s += v.x * v.x + v.y * v.y + v.z * v.z + v.w * v.w;
    }
    int e = r >> 3;
    int h = r & 7;
    float sg = __uint_as_float(seg[(size_t)index[e] * H_DIM + h]);
    out[r] = alpha[r] / (s_natt[h] * sqrtf(sg + s) + EPSF);
}

extern "C" void kernel_launch(void* const* d_in, const int* in_sizes, int n_in,
                              void* d_out, int out_size, void* d_ws, size_t ws_size,
                              hipStream_t stream) {
    const float* x     = (const float*)d_in[0];
    const float* att_l = (const float*)d_in[1];
    const float* att_r = (const float*)d_in[2];
    const float* alpha = (const float*)d_in[3];
    const int*   index = (const int*)d_in[4];

    const int E    = in_sizes[4];
    const int rows = E * H_DIM;

    size_t seg_pad = ((size_t)SEG_WORDS * 4 + 255) / 256 * 256;
    size_t need    = seg_pad + (size_t)rows * sizeof(float);

    unsigned* seg = (unsigned*)d_ws;
    lip_zero<<<(SEG_WORDS + 255) / 256, 256, 0, stream>>>(seg, SEG_WORDS);

    if (ws_size >= need) {
        float* norm_x = (float*)((char*)d_ws + seg_pad);
        lip_pass1_pc<<<2048, 256, 0, stream>>>(x, index, norm_x, seg, rows);
        int t2 = E * 2;
        lip_pass2<<<(t2 + 255) / 256, 256, 0, stream>>>(
            norm_x, alpha, index, seg, att_l, att_r, (float*)d_out, t2);
    } else {
        lip_pass1_merged<<<2048, 256, 0, stream>>>(x, index, seg, rows * 4);
        lip_pass2_recompute<<<(rows + 255) / 256, 256, 0, stream>>>(
            x, alpha, index, seg, att_l, att_r, (float*)d_out, rows);
    }
}

// Round 14
// 130.562 us; speedup vs baseline: 1.1443x; 1.0903x over previous
//
#include <hip/hip_runtime.h>
#include <math.h>

#define EPSF 1e-12f
#define ATT_NORM_F 4.0f
#define H_DIM 8
#define C_DIM 16
#define N_NODES 100000
#define SEG_WORDS (N_NODES * H_DIM)   // 800000 words = 3.2 MB

#define TPB 512                       // 8 waves: 6 streamers + 2 scatter
#define NBLK 1024                     // 4 blocks/CU x 8 waves = 32 waves/CU
#define CHUNK 384                     // rows per phase per block
#define PASSES 4                      // 96 rows per pass

typedef float v4f __attribute__((ext_vector_type(4)));

// ---------------------------------------------------------------------------
// Zero the seg table.
// ---------------------------------------------------------------------------
__global__ __launch_bounds__(256) void lip_zero(unsigned* __restrict__ p, int n)
{
    int i = blockIdx.x * 256 + threadIdx.x;
    if (i < n) p[i] = 0u;
}

// ---------------------------------------------------------------------------
// LDS-only barrier (R11): orders LDS produce/consume without draining VMEM.
// __syncthreads would force vmcnt(0) each phase, draining the scatter waves'
// in-flight atomics and the streamers' nt-loads; lgkmcnt(0) covers the only
// real cross-wave dependency (LDS).
// ---------------------------------------------------------------------------
__device__ __forceinline__ void lds_barrier()
{
    asm volatile("s_waitcnt lgkmcnt(0)\n\ts_barrier" ::: "memory");
}

// ---------------------------------------------------------------------------
// Pass 1, producer/consumer, 6:2 wave split @ 512 threads.
// vs R11 (3:1 @ 256, best=130us): machine-wide streamer waves IDENTICAL
// (1024x6 = 2048x3 = 6144 -> same HBM issue capacity), but each scatter
// wave's required atomic rate halves (192 rows over a 2x-longer phase:
// ~19/us vs ~38/us against the ~42/us vmcnt-queue cap) and per-row barrier
// count halves. Clean A/B on the scatter-queue-saturation hypothesis.
// Single seg table + device-scope atomicMax (scope irrelevant: R6/R7/R12).
// ---------------------------------------------------------------------------
__global__ __launch_bounds__(TPB) void lip_pass1_pc(
    const float* __restrict__ x, const int* __restrict__ index,
    float* __restrict__ norm_x, unsigned* __restrict__ seg, int rows)
{
    __shared__ float buf[2][CHUNK];

    const int t = threadIdx.x;
    const int w = t >> 6;                     // wave id 0..7
    const int nchunks = (rows + CHUNK - 1) / CHUNK;
    const v4f* x4 = (const v4f*)x;

    const int rloc = t >> 2;                  // 0..95 (valid for w<6)
    const int lane = t & 3;

    for (int p = 0; ; ++p) {
        int c  = blockIdx.x + p * gridDim.x;          // chunk to stream
        int cp = c - gridDim.x;                       // chunk to scatter
        bool do_s = (c < nchunks);
        bool do_a = (p > 0) && (cp < nchunks);
        if (!do_s && !do_a) break;                    // block-uniform exit

        if (w < 6) {
            if (do_s) {
                int base = c * CHUNK;
                float* b = buf[p & 1];
                #pragma unroll
                for (int j = 0; j < PASSES; ++j) {
                    int r = base + j * 96 + rloc;
                    if (r < rows) {
                        v4f v = __builtin_nontemporal_load(&x4[(size_t)r * 4 + lane]);
                        float s = v.x * v.x + v.y * v.y + v.z * v.z + v.w * v.w;
                        s += __shfl_xor(s, 1);
                        s += __shfl_xor(s, 2);
                        if (lane == 0) {
                            norm_x[r] = s;    // cache-allocating -> LLC for pass2
                            b[j * 96 + rloc] = s;
                        }
                    }
                }
            }
        } else {
            if (do_a) {
                int base = cp * CHUNK;
                const float* b = buf[(p & 1) ^ 1];
                int i0 = t - 384;                     // 0..127
                #pragma unroll
                for (int k = 0; k < 3; ++k) {
                    int i = k * 128 + i0;             // 0..383
                    int r = base + i;
                    if (r < rows) {
                        float s = b[i];
                        int e = r >> 3;
                        int h = r & 7;
                        // s >= 0: float bits monotone under unsigned max
                        atomicMax(&seg[(size_t)index[e] * H_DIM + h],
                                  __float_as_uint(s));
                    }
                }
            }
        }
        lds_barrier();   // publishes buf[p&1]; confirms buf[(p-1)&1] drained
    }
}

// ---------------------------------------------------------------------------
// Pass 2 (one-shot): out = alpha / (natt * sqrt(seg[idx] + norm_x) + eps)
// One thread per 4 consecutive heads (float4). seg gather L2-resident;
// norm_x LLC-hot; alpha/out nt streams.
// ---------------------------------------------------------------------------
__global__ __launch_bounds__(256) void lip_pass2(
    const float* __restrict__ norm_x, const float* __restrict__ alpha,
    const int* __restrict__ index, const unsigned int* __restrict__ seg,
    const float* __restrict__ att_l, const float* __restrict__ att_r,
    float* __restrict__ out, int total)   // total = E*2
{
    __shared__ float s_natt[H_DIM];
    int t = threadIdx.x;
    if (t < H_DIM) {
        float s = 0.f;
        #pragma unroll
        for (int c = 0; c < C_DIM; ++c) {
            float l = att_l[t * C_DIM + c];
            float r = att_r[t * C_DIM + c];
            s += l * l + r * r;
        }
        s_natt[t] = ATT_NORM_F * sqrtf(s);
    }
    __syncthreads();

    int tid = blockIdx.x * 256 + t;
    if (tid >= total) return;

    int e    = tid >> 1;
    int half = tid & 1;
    int idx  = index[e];

    const v4f* nx4 = (const v4f*)norm_x;
    const v4f* al4 = (const v4f*)alpha;
    const v4f* sg4 = (const v4f*)seg;       // bits are non-negative floats

    v4f nx = nx4[tid];                               // LLC-hot
    v4f al = __builtin_nontemporal_load(&al4[tid]);  // cold stream
    v4f sg = sg4[(size_t)idx * 2 + half];            // L2-resident gather

    int h0 = half * 4;
    v4f o;
    o.x = al.x / (s_natt[h0 + 0] * sqrtf(sg.x + nx.x) + EPSF);
    o.y = al.y / (s_natt[h0 + 1] * sqrtf(sg.y + nx.y) + EPSF);
    o.z = al.z / (s_natt[h0 + 2] * sqrtf(sg.z + nx.z) + EPSF);
    o.w = al.w / (s_natt[h0 + 3] * sqrtf(sg.w + nx.w) + EPSF);
    __builtin_nontemporal_store(o, &((v4f*)out)[tid]);
}

// ---------------------------------------------------------------------------
// Fallbacks (ws too small): merged pass1 + recompute pass2 (R4-style).
// ---------------------------------------------------------------------------
__global__ __launch_bounds__(256) void lip_pass1_merged(
    const float* __restrict__ x, const int* __restrict__ index,
    unsigned int* __restrict__ seg, int total /*rows*4*/)
{
    const int stride = gridDim.x * 256;
    const int s0 = blockIdx.x * 256 + threadIdx.x;
    const int lane = s0 & 3;
    const v4f* x4 = (const v4f*)x;
    #pragma unroll 4
    for (int s = s0; s < total; s += stride) {
        v4f v = __builtin_nontemporal_load(&x4[s]);
        float sum = v.x * v.x + v.y * v.y + v.z * v.z + v.w * v.w;
        sum += __shfl_xor(sum, 1);
        sum += __shfl_xor(sum, 2);
        if (lane == 0) {
            int r = s >> 2;
            int e = r >> 3, h = r & 7;
            atomicMax(&seg[(size_t)index[e] * H_DIM + h], __float_as_uint(sum));
        }
    }
}

__global__ __launch_bounds__(256) void lip_pass2_recompute(
    const float* __restrict__ x, const float* __restrict__ alpha,
    const int* __restrict__ index, const unsigned int* __restrict__ seg,
    const float* __restrict__ att_l, const float* __restrict__ att_r,
    float* __restrict__ out, int rows)
{
    __shared__ float s_natt[H_DIM];
    int t = threadIdx.x;
    if (t < H_DIM) {
        float s = 0.f;
        #pragma unroll
        for (int c = 0; c < C_DIM; ++c) {
            float l = att_l[t * C_DIM + c];
            float r = att_r[t * C_DIM + c];
            s += l * l + r * r;
        }
        s_natt[t] = ATT_NORM_F * sqrtf(s);
    }
    __syncthreads();

    int r = blockIdx.x * blockDim.x + t;
    if (r >= rows) return;

    const float4* x4 = (const float4*)x;
    float s = 0.f;
    #pragma unroll
    for (int q = 0; q < 4; ++q) {
        float4 v = x4[(size_t)r * 4 + q];
        s += v.x * v.x + v.y * v.y + v.z * v.z + v.w * v.w;
    }
    int e = r >> 3;
    int h = r & 7;
    float sg = __uint_as_float(seg[(size_t)index[e] * H_DIM + h]);
    out[r] = alpha[r] / (s_natt[h] * sqrtf(sg + s) + EPSF);
}

extern "C" void kernel_launch(void* const* d_in, const int* in_sizes, int n_in,
                              void* d_out, int out_size, void* d_ws, size_t ws_size,
                              hipStream_t stream) {
    const float* x     = (const float*)d_in[0];
    const float* att_l = (const float*)d_in[1];
    const float* att_r = (const float*)d_in[2];
    const float* alpha = (const float*)d_in[3];
    const int*   index = (const int*)d_in[4];

    const int E    = in_sizes[4];
    const int rows = E * H_DIM;

    size_t seg_pad = ((size_t)SEG_WORDS * 4 + 255) / 256 * 256;
    size_t need    = seg_pad + (size_t)rows * sizeof(float);

    unsigned* seg = (unsigned*)d_ws;
    lip_zero<<<(SEG_WORDS + 255) / 256, 256, 0, stream>>>(seg, SEG_WORDS);

    if (ws_size >= need) {
        float* norm_x = (float*)((char*)d_ws + seg_pad);
        lip_pass1_pc<<<NBLK, TPB, 0, stream>>>(x, index, norm_x, seg, rows);
        int t2 = E * 2;
        lip_pass2<<<(t2 + 255) / 256, 256, 0, stream>>>(
            norm_x, alpha, index, seg, att_l, att_r, (float*)d_out, t2);
    } else {
        lip_pass1_merged<<<2048, 256, 0, stream>>>(x, index, seg, rows * 4);
        lip_pass2_recompute<<<(rows + 255) / 256, 256, 0, stream>>>(
            x, alpha, index, seg, att_l, att_r, (float*)d_out, rows);
    }
}

// Round 15
// 128.394 us; speedup vs baseline: 1.1637x; 1.0169x over previous
//
#include <hip/hip_runtime.h>
#include <math.h>

#define EPSF 1e-12f
#define ATT_NORM_F 4.0f
#define H_DIM 8
#define C_DIM 16
#define N_NODES 100000
#define SEG_WORDS (N_NODES * H_DIM)   // 800000 words = 3.2 MB

#define CHUNK 192                     // rows per phase per block (= 3*64)
#define PASSES 4                      // row-passes per phase (48 rows each)

typedef float v4f __attribute__((ext_vector_type(4)));

// ---------------------------------------------------------------------------
// Zero the seg table + precompute natt[8] = 4*sqrt(|att_l|^2+|att_r|^2) into
// ws so pass2 needs no per-block preamble (no LDS, no __syncthreads).
// ---------------------------------------------------------------------------
__global__ __launch_bounds__(256) void lip_zero(
    unsigned* __restrict__ p, int n,
    const float* __restrict__ att_l, const float* __restrict__ att_r,
    float* __restrict__ natt)
{
    int i = blockIdx.x * 256 + threadIdx.x;
    if (i < n) p[i] = 0u;
    if (blockIdx.x == 0 && threadIdx.x < H_DIM) {
        int t = threadIdx.x;
        float s = 0.f;
        #pragma unroll
        for (int c = 0; c < C_DIM; ++c) {
            float l = att_l[t * C_DIM + c];
            float r = att_r[t * C_DIM + c];
            s += l * l + r * r;
        }
        natt[t] = ATT_NORM_F * sqrtf(s);
    }
}

// ---------------------------------------------------------------------------
// LDS-only barrier (R11): orders LDS produce/consume without draining VMEM.
// __syncthreads would force vmcnt(0) each phase, draining the scatter wave's
// in-flight atomics and the streamers' nt-loads; lgkmcnt(0) covers the only
// real cross-wave dependency (LDS).
// ---------------------------------------------------------------------------
__device__ __forceinline__ void lds_barrier()
{
    asm volatile("s_waitcnt lgkmcnt(0)\n\ts_barrier" ::: "memory");
}

// ---------------------------------------------------------------------------
// Pass 1 (R11 verbatim — best measured): producer/consumer 3:1 @ 256.
// Waves 0-2 stream x (nt) + write norm_x (cache-allocating -> LLC for
// pass2) + publish row norms through double-buffered LDS; wave 3 fires the
// device-scope atomicMax scatter (fire-and-forget, never drained mid-kernel).
// ---------------------------------------------------------------------------
__global__ __launch_bounds__(256) void lip_pass1_pc(
    const float* __restrict__ x, const int* __restrict__ index,
    float* __restrict__ norm_x, unsigned* __restrict__ seg, int rows)
{
    __shared__ float buf[2][CHUNK];

    const int t = threadIdx.x;
    const int w = t >> 6;                     // wave id 0..3
    const int nchunks = (rows + CHUNK - 1) / CHUNK;
    const v4f* x4 = (const v4f*)x;

    const int rloc = t >> 2;                  // 0..47 (valid for w<3)
    const int lane = t & 3;

    for (int p = 0; ; ++p) {
        int c  = blockIdx.x + p * gridDim.x;          // chunk to stream
        int cp = c - gridDim.x;                       // chunk to scatter
        bool do_s = (c < nchunks);
        bool do_a = (p > 0) && (cp < nchunks);
        if (!do_s && !do_a) break;                    // block-uniform exit

        if (w < 3) {
            if (do_s) {
                int base = c * CHUNK;
                float* b = buf[p & 1];
                #pragma unroll
                for (int j = 0; j < PASSES; ++j) {
                    int r = base + j * 48 + rloc;
                    if (r < rows) {
                        v4f v = __builtin_nontemporal_load(&x4[(size_t)r * 4 + lane]);
                        float s = v.x * v.x + v.y * v.y + v.z * v.z + v.w * v.w;
                        s += __shfl_xor(s, 1);
                        s += __shfl_xor(s, 2);
                        if (lane == 0) {
                            norm_x[r] = s;    // cache-allocating -> LLC for pass2
                            b[j * 48 + rloc] = s;
                        }
                    }
                }
            }
        } else {
            if (do_a) {
                int base = cp * CHUNK;
                const float* b = buf[(p & 1) ^ 1];
                int ln = t & 63;
                #pragma unroll
                for (int k = 0; k < 3; ++k) {
                    int i = k * 64 + ln;              // 0..191
                    int r = base + i;
                    if (r < rows) {
                        float s = b[i];
                        int e = r >> 3;
                        int h = r & 7;
                        // s >= 0: float bits monotone under unsigned max
                        atomicMax(&seg[(size_t)index[e] * H_DIM + h],
                                  __float_as_uint(s));
                    }
                }
            }
        }
        lds_barrier();   // publishes buf[p&1]; confirms buf[(p-1)&1] drained
    }
}

// ---------------------------------------------------------------------------
// Pass 2 (one-shot, preamble-free): out = alpha * rcp(natt*sqrt(seg+nx)+eps)
// natt comes from ws (precomputed by lip_zero) as one 16B cached load ->
// no LDS, no __syncthreads, no per-block att reads. Fast v_rcp/v_sqrt
// (rel err ~3e-7 << 9.5e-4 threshold) replace the Newton-divide.
// ---------------------------------------------------------------------------
__global__ __launch_bounds__(256) void lip_pass2(
    const float* __restrict__ norm_x, const float* __restrict__ alpha,
    const int* __restrict__ index, const unsigned int* __restrict__ seg,
    const float* __restrict__ natt, float* __restrict__ out, int total)
{
    int tid = blockIdx.x * 256 + threadIdx.x;
    if (tid >= total) return;

    int e    = tid >> 1;
    int half = tid & 1;
    int idx  = index[e];

    const v4f* nx4 = (const v4f*)norm_x;
    const v4f* al4 = (const v4f*)alpha;
    const v4f* sg4 = (const v4f*)seg;       // bits are non-negative floats

    v4f na = ((const v4f*)natt)[half];               // L2-hot broadcast
    v4f nx = nx4[tid];                               // LLC-hot
    v4f al = __builtin_nontemporal_load(&al4[tid]);  // cold stream
    v4f sg = sg4[(size_t)idx * 2 + half];            // L2-resident gather

    v4f o;
    o.x = al.x * __builtin_amdgcn_rcpf(na.x * __builtin_amdgcn_sqrtf(sg.x + nx.x) + EPSF);
    o.y = al.y * __builtin_amdgcn_rcpf(na.y * __builtin_amdgcn_sqrtf(sg.y + nx.y) + EPSF);
    o.z = al.z * __builtin_amdgcn_rcpf(na.z * __builtin_amdgcn_sqrtf(sg.z + nx.z) + EPSF);
    o.w = al.w * __builtin_amdgcn_rcpf(na.w * __builtin_amdgcn_sqrtf(sg.w + nx.w) + EPSF);
    __builtin_nontemporal_store(o, &((v4f*)out)[tid]);
}

// ---------------------------------------------------------------------------
// Fallbacks (ws too small): merged pass1 + recompute pass2 (R4-style).
// ---------------------------------------------------------------------------
__global__ __launch_bounds__(256) void lip_pass1_merged(
    const float* __restrict__ x, const int* __restrict__ index,
    unsigned int* __restrict__ seg, int total /*rows*4*/)
{
    const int stride = gridDim.x * 256;
    const int s0 = blockIdx.x * 256 + threadIdx.x;
    const int lane = s0 & 3;
    const v4f* x4 = (const v4f*)x;
    #pragma unroll 4
    for (int s = s0; s < total; s += stride) {
        v4f v = __builtin_nontemporal_load(&x4[s]);
        float sum = v.x * v.x + v.y * v.y + v.z * v.z + v.w * v.w;
        sum += __shfl_xor(sum, 1);
        sum += __shfl_xor(sum, 2);
        if (lane == 0) {
            int r = s >> 2;
            int e = r >> 3, h = r & 7;
            atomicMax(&seg[(size_t)index[e] * H_DIM + h], __float_as_uint(sum));
        }
    }
}

__global__ __launch_bounds__(256) void lip_pass2_recompute(
    const float* __restrict__ x, const float* __restrict__ alpha,
    const int* __restrict__ index, const unsigned int* __restrict__ seg,
    const float* __restrict__ att_l, const float* __restrict__ att_r,
    float* __restrict__ out, int rows)
{
    __shared__ float s_natt[H_DIM];
    int t = threadIdx.x;
    if (t < H_DIM) {
        float s = 0.f;
        #pragma unroll
        for (int c = 0; c < C_DIM; ++c) {
            float l = att_l[t * C_DIM + c];
            float r = att_r[t * C_DIM + c];
            s += l * l + r * r;
        }
        s_natt[t] = ATT_NORM_F * sqrtf(s);
    }
    __syncthreads();

    int r = blockIdx.x * blockDim.x + t;
    if (r >= rows) return;

    const float4* x4 = (const float4*)x;
    float s = 0.f;
    #pragma unroll
    for (int q = 0; q < 4; ++q) {
        float4 v = x4[(size_t)r * 4 + q];
        s += v.x * v.x + v.y * v.y + v.z * v.z + v.w * v.w;
    }
    int e = r >> 3;
    int h = r & 7;
    float sg = __uint_as_float(seg[(size_t)index[e] * H_DIM + h]);
    out[r] = alpha[r] / (s_natt[h] * sqrtf(sg + s) + EPSF);
}

extern "C" void kernel_launch(void* const* d_in, const int* in_sizes, int n_in,
                              void* d_out, int out_size, void* d_ws, size_t ws_size,
                              hipStream_t stream) {
    const float* x     = (const float*)d_in[0];
    const float* att_l = (const float*)d_in[1];
    const float* att_r = (const float*)d_in[2];
    const float* alpha = (const float*)d_in[3];
    const int*   index = (const int*)d_in[4];

    const int E    = in_sizes[4];
    const int rows = E * H_DIM;

    // ws layout: seg[SEG_WORDS] | natt[8] (256B slot) | norm_x[rows]
    size_t seg_pad = ((size_t)SEG_WORDS * 4 + 255) / 256 * 256;
    size_t nx_off  = seg_pad + 256;
    size_t need    = nx_off + (size_t)rows * sizeof(float);

    unsigned* seg  = (unsigned*)d_ws;
    float*    natt = (float*)((char*)d_ws + seg_pad);

    if (ws_size >= need) {
        float* norm_x = (float*)((char*)d_ws + nx_off);
        lip_zero<<<(SEG_WORDS + 255) / 256, 256, 0, stream>>>(
            seg, SEG_WORDS, att_l, att_r, natt);
        lip_pass1_pc<<<2048, 256, 0, stream>>>(x, index, norm_x, seg, rows);
        int t2 = E * 2;
        lip_pass2<<<(t2 + 255) / 256, 256, 0, stream>>>(
            norm_x, alpha, index, seg, natt, (float*)d_out, t2);
    } else {
        lip_zero<<<(SEG_WORDS + 255) / 256, 256, 0, stream>>>(
            seg, SEG_WORDS, att_l, att_r, natt);
        lip_pass1_merged<<<2048, 256, 0, stream>>>(x, index, seg, rows * 4);
        lip_pass2_recompute<<<(rows + 255) / 256, 256, 0, stream>>>(
            x, alpha, index, seg, att_l, att_r, (float*)d_out, rows);
    }
}